// Round 12
// baseline (479.702 us; speedup 1.0000x reference)
//
#include <hip/hip_runtime.h>
#include <hip/hip_bf16.h>

#define NPIX 4096
#define CIN  256
#define DK   32

typedef __attribute__((ext_vector_type(8))) short short8;     // 8 bf16 = one MFMA A/B frag reg group
typedef __attribute__((ext_vector_type(16))) float f32x16;    // 32x32 C/D frag

__device__ __forceinline__ unsigned short f2bf(float f) {
    unsigned int u = __float_as_uint(f);
    return (unsigned short)((u + 0x7fffu + ((u >> 16) & 1u)) >> 16);   // RNE
}
__device__ __forceinline__ float bf2f(unsigned short h) {
    return __uint_as_float(((unsigned int)h) << 16);
}
// packed fp32x2 -> bf16x2 via v_cvt_pk_bf16_f32 (RNE), low short = a
__device__ __forceinline__ unsigned int f2bf2(float a, float b) {
    __hip_bfloat162 h = __float22bfloat162_rn(make_float2(a, b));
    unsigned int u;
    __builtin_memcpy(&u, &h, 4);
    return u;
}

// ---------------------------------------------------------------------------
// Weight prep: wq/wk hi+residual B-frags, wv hi B-frags.
// grid (16 kchunks, 12), 64 threads.
__global__ void wprep_kernel(const float* __restrict__ wq, const float* __restrict__ wk,
                             const float* __restrict__ wv,
                             unsigned short* __restrict__ wqh, unsigned short* __restrict__ wql,
                             unsigned short* __restrict__ wkh, unsigned short* __restrict__ wkl,
                             unsigned short* __restrict__ wvh) {
    const int lane = threadIdx.x & 63, li = lane & 31, hi = lane >> 5;
    const int kc = blockIdx.x, y = blockIdx.y;
    if (y < 4) {
        const float* m = (y < 2) ? wq : wk;
        short8 h8, l8;
#pragma unroll
        for (int e = 0; e < 8; ++e) {
            float v = m[li * CIN + kc * 16 + hi * 8 + e];
            unsigned short hb = f2bf(v);
            h8[e] = (short)hb;
            l8[e] = (short)f2bf(v - bf2f(hb));
        }
        unsigned short* dst = (y == 0) ? wqh : (y == 1) ? wql : (y == 2) ? wkh : wkl;
        *reinterpret_cast<short8*>(&dst[kc * 512 + lane * 8]) = (y & 1) ? l8 : h8;
    } else {
        const int cblk = y - 4;
        short8 h8;
#pragma unroll
        for (int e = 0; e < 8; ++e)
            h8[e] = (short)f2bf(wv[(cblk * 32 + li) * CIN + kc * 16 + hi * 8 + e]);
        *reinterpret_cast<short8*>(&wvh[(cblk * 16 + kc) * 512 + lane * 8]) = h8;
    }
}

// ---------------------------------------------------------------------------
// Fused prep + Q/K/V projection (r10 version — LDS-staged, measured-good).
// grid (128, 4), block 512.
__global__ __launch_bounds__(512) void projall_kernel(
        const float* __restrict__ x,
        const unsigned short* __restrict__ wqh, const unsigned short* __restrict__ wql,
        const unsigned short* __restrict__ wkh, const unsigned short* __restrict__ wkl,
        const unsigned short* __restrict__ wvh,
        const float* __restrict__ bq, const float* __restrict__ bk, const float* __restrict__ bv,
        unsigned short* __restrict__ qfrag, unsigned short* __restrict__ kfrag,
        unsigned short* __restrict__ vfrag) {
    __shared__ float xs[64][36];
    __shared__ unsigned short xhf[16 * 512];
    __shared__ unsigned short xlf[16 * 512];
    __shared__ unsigned short ts[2][32][40];

    const int t = threadIdx.x, lane = t & 63, li = lane & 31, hi = lane >> 5, w = t >> 6;
    const int nblk = blockIdx.x, b = blockIdx.y;
    const int n0 = nblk * 32;

    for (int cb = 0; cb < 4; ++cb) {
        {
            int c = t >> 3, n4 = (t & 7) * 4;
            float4 v = *reinterpret_cast<const float4*>(
                &x[(size_t)(b * CIN + cb * 64 + c) * NPIX + n0 + n4]);
            xs[c][n4 + 0] = v.x; xs[c][n4 + 1] = v.y;
            xs[c][n4 + 2] = v.z; xs[c][n4 + 3] = v.w;
        }
        __syncthreads();
        {
            const int kc = w & 3;
            const bool isL = (w >= 4);
            short8 f;
#pragma unroll
            for (int e = 0; e < 8; ++e) {
                float v = xs[kc * 16 + hi * 8 + e][li];
                unsigned short hb = f2bf(v);
                f[e] = isL ? (short)f2bf(v - bf2f(hb)) : (short)hb;
            }
            unsigned short* dst = isL ? xlf : xhf;
            *reinterpret_cast<short8*>(&dst[(cb * 4 + kc) * 512 + lane * 8]) = f;
        }
        __syncthreads();
    }

    if (w < 2) {
        const unsigned short* wh = (w == 0) ? wqh : wkh;
        const unsigned short* wl = (w == 0) ? wql : wkl;
        const float* bias = (w == 0) ? bq : bk;
        f32x16 acc;
#pragma unroll
        for (int r = 0; r < 16; ++r) acc[r] = 0.f;
        for (int kc = 0; kc < 16; ++kc) {
            short8 ah = *reinterpret_cast<const short8*>(&xhf[kc * 512 + lane * 8]);
            short8 al = *reinterpret_cast<const short8*>(&xlf[kc * 512 + lane * 8]);
            short8 whf = *reinterpret_cast<const short8*>(&wh[kc * 512 + lane * 8]);
            short8 wlf = *reinterpret_cast<const short8*>(&wl[kc * 512 + lane * 8]);
            acc = __builtin_amdgcn_mfma_f32_32x32x16_bf16(ah, whf, acc, 0, 0, 0);
            acc = __builtin_amdgcn_mfma_f32_32x32x16_bf16(al, whf, acc, 0, 0, 0);
            acc = __builtin_amdgcn_mfma_f32_32x32x16_bf16(ah, wlf, acc, 0, 0, 0);
        }
        const float bs = bias[li];
#pragma unroll
        for (int r = 0; r < 16; ++r) {
            int row = (r & 3) + 8 * (r >> 2) + 4 * hi;
            ts[w][row][li] = f2bf(acc[r] + bs);
        }
        unsigned short* dstf = (w == 0) ? qfrag : kfrag;
#pragma unroll
        for (int dh = 0; dh < 2; ++dh) {
            short8 f = *reinterpret_cast<const short8*>(&ts[w][li][dh * 16 + hi * 8]);
            *reinterpret_cast<short8*>(
                &dstf[((size_t)(b * 128 + nblk) * 2 + dh) * 512 + lane * 8]) = f;
        }
    } else {
        const int w2 = w - 2;
        const int njob = (w2 < 2) ? 2 : 1;
        for (int jj = 0; jj < njob; ++jj) {
            const int cblk = w2 + jj * 6;
            f32x16 acc;
#pragma unroll
            for (int r = 0; r < 16; ++r) acc[r] = 0.f;
            for (int kc = 0; kc < 16; ++kc) {
                short8 xb = *reinterpret_cast<const short8*>(&xhf[kc * 512 + lane * 8]);
                short8 wf = *reinterpret_cast<const short8*>(&wvh[(cblk * 16 + kc) * 512 + lane * 8]);
                acc = __builtin_amdgcn_mfma_f32_32x32x16_bf16(xb, wf, acc, 0, 0, 0);
            }
            const float bvv = bv[cblk * 32 + li];
#pragma unroll
            for (int g = 0; g < 2; ++g) {
                short8 sv;
#pragma unroll
                for (int e = 0; e < 8; ++e) sv[e] = (short)f2bf(acc[g * 8 + e] + bvv);
                *reinterpret_cast<short8*>(
                    &vfrag[((size_t)(b * 8 + cblk) * 256 + nblk * 2 + g) * 512 + lane * 8]) = sv;
            }
        }
    }
}

// ---------------------------------------------------------------------------
// Fused attention, j-split, symmetric waves; deep pipeline:
//  - Ps has 4 buffers (64 KB): E runs 2 steps ahead, barrier every 2 steps
//    (9 drains instead of 17 — each __syncthreads drains vmcnt(0), §5 m97).
//  - V regs reloaded per-kc right after last use (loads covered by the
//    remainder of the step instead of all piling up at the barrier drain).
// Block = 512 thr (8 waves), grid 512 = 2 blocks/CU.
__global__ __launch_bounds__(512, 4) void attnv_kernel(
        const unsigned short* __restrict__ qfrag, const unsigned short* __restrict__ kfrag,
        const unsigned short* __restrict__ vfrag, unsigned short* __restrict__ opart,
        float* __restrict__ lpart, float* __restrict__ out) {
    __shared__ unsigned short Ps[8 * 8 * 512];   // [it*4+buf(s&3)][jg 8][lane*8], 64 KB
    __shared__ float sred[2][4][32];

    const int t = threadIdx.x, lane = t & 63, li = lane & 31, hi = lane >> 5, w = t >> 6;
    const int blk = blockIdx.x;
    const int xcd = blk & 7, slot = blk >> 3;
    const int jh = slot & 1, ps = slot >> 1;
    const int b = xcd >> 1;
    const int ipos = (xcd & 1) * 32 + ps;          // 64-i tile in [0,64)
    const int it = w >> 2, sl = w & 3;             // E unit
    const int cq = w;                              // PV unit (32 c)

    short8 qb0, qb1;
    {
        size_t qoff = ((size_t)(b * 128 + ipos * 2 + it) * 2) * 512 + lane * 8;
        qb0 = *reinterpret_cast<const short8*>(&qfrag[qoff]);
        qb1 = *reinterpret_cast<const short8*>(&qfrag[qoff + 512]);
    }
    float ssum = 0.f;

    f32x16 acc0, acc1;
#pragma unroll
    for (int r = 0; r < 16; ++r) { acc0[r] = 0.f; acc1[r] = 0.f; }

    short8 kp[2][2];                               // K double-buffer (step parity)
    short8 vp[8];                                  // V regs (rolling reload)

    auto kload = [&](int s) {
        size_t koff = ((size_t)(b * 128 + jh * 64 + s * 4 + sl) * 2) * 512 + lane * 8;
        kp[s & 1][0] = *reinterpret_cast<const short8*>(&kfrag[koff]);
        kp[s & 1][1] = *reinterpret_cast<const short8*>(&kfrag[koff + 512]);
    };
    auto do_E = [&](int s) {                       // consumes kp[s&1] (preloaded for s)
        f32x16 e;
#pragma unroll
        for (int r = 0; r < 16; ++r) e[r] = 0.f;
        e = __builtin_amdgcn_mfma_f32_32x32x16_bf16(kp[s & 1][0], qb0, e, 0, 0, 0);
        e = __builtin_amdgcn_mfma_f32_32x32x16_bf16(kp[s & 1][1], qb1, e, 0, 0, 0);
        const int buf = s & 3;
#pragma unroll
        for (int g = 0; g < 2; ++g) {
            float p0 = __expf(e[g * 8 + 0]), p1 = __expf(e[g * 8 + 1]);
            float p2 = __expf(e[g * 8 + 2]), p3 = __expf(e[g * 8 + 3]);
            float p4 = __expf(e[g * 8 + 4]), p5 = __expf(e[g * 8 + 5]);
            float p6 = __expf(e[g * 8 + 6]), p7 = __expf(e[g * 8 + 7]);
            ssum += ((p0 + p1) + (p2 + p3)) + ((p4 + p5) + (p6 + p7));
            uint4 pk;
            pk.x = f2bf2(p0, p1); pk.y = f2bf2(p2, p3);
            pk.z = f2bf2(p4, p5); pk.w = f2bf2(p6, p7);
            *reinterpret_cast<uint4*>(
                &Ps[((it * 4 + buf) * 8 + sl * 2 + g) * 512 + lane * 8]) = pk;
        }
    };
    auto vbase = [&](int s) {
        return ((size_t)(b * 8 + cq) * 256 + jh * 128 + s * 8) * 512 + lane * 8;
    };

    // prologue: E(0), E(1) into bufs 0,1; K(2),K(3) staged; V(0) staged.
    kload(0); do_E(0);
    kload(1); do_E(1);
    {
        size_t vb = vbase(0);
#pragma unroll
        for (int kc = 0; kc < 8; ++kc)
            vp[kc] = *reinterpret_cast<const short8*>(&vfrag[vb + kc * 512]);
    }
    kload(2); kload(3);
    __syncthreads();

#pragma unroll 1
    for (int s = 0; s < 16; ++s) {
        if (s + 2 < 16) {
            do_E(s + 2);                           // consumes kp[s&1]; writes buf (s+2)&3
            if (s + 4 < 16) kload(s + 4);          // refills kp[s&1]; covered by PV below
        }
        const int buf = s & 3;
        const size_t vbn = (s + 1 < 16) ? vbase(s + 1) : 0;
#pragma unroll
        for (int kc = 0; kc < 8; ++kc) {
            short8 B0 = *reinterpret_cast<const short8*>(&Ps[(buf * 8 + kc) * 512 + lane * 8]);
            short8 B1 = *reinterpret_cast<const short8*>(&Ps[((4 + buf) * 8 + kc) * 512 + lane * 8]);
            acc0 = __builtin_amdgcn_mfma_f32_32x32x16_bf16(vp[kc], B0, acc0, 0, 0, 0);
            acc1 = __builtin_amdgcn_mfma_f32_32x32x16_bf16(vp[kc], B1, acc1, 0, 0, 0);
            if (s + 1 < 16)                        // rolling reload right after last use
                vp[kc] = *reinterpret_cast<const short8*>(&vfrag[vbn + kc * 512]);
        }
        if (s & 1) __syncthreads();                // barrier every 2 steps (9 total)
    }

    // row sums: wave w holds (it, sl) partial over its 32-j slice
    ssum += __shfl_xor(ssum, 32);
    if (lane < 32) sred[it][sl][li] = ssum;
    __syncthreads();
    if (sl == 0 && lane < 32) {
        float lt = sred[it][0][li] + sred[it][1][li] + sred[it][2][li] + sred[it][3][li];
        lpart[((size_t)jh * 4 + b) * NPIX + ipos * 64 + it * 32 + li] = lt;
    }

    // partial O (linear [b][c][i]): jh0 fp32 parked in out, jh1 bf16 in opart
#pragma unroll
    for (int itt = 0; itt < 2; ++itt) {
        const f32x16& A = itt ? acc1 : acc0;
#pragma unroll
        for (int r = 0; r < 16; ++r) {
            int c = cq * 32 + (r & 3) + 8 * (r >> 2) + 4 * hi;
            size_t idx = (size_t)(b * CIN + c) * NPIX + ipos * 64 + itt * 32 + li;
            if (jh == 0) out[idx] = A[r];
            else         opart[idx] = f2bf(A[r]);
        }
    }
}

// ---------------------------------------------------------------------------
// Merge: out = gamma * (O0 + O1) / (l0 + l1) + x.  ~56 MB streaming.
// grid 2048, block 256; thread handles 8 consecutive i (opart read = one 16B).
__global__ __launch_bounds__(256) void merge_kernel(
        const unsigned short* __restrict__ opart, const float* __restrict__ lpart,
        const float* __restrict__ xin, const float* __restrict__ gamma,
        float* __restrict__ out) {
    const size_t idx8 = ((size_t)blockIdx.x * 256 + threadIdx.x) * 8;
    const size_t i  = idx8 & (NPIX - 1);
    const size_t b  = idx8 >> 20;                 // idx8 / (CIN*NPIX)
    short8 o1v = *reinterpret_cast<const short8*>(&opart[idx8]);
    float4 o00 = *reinterpret_cast<const float4*>(&out[idx8]);
    float4 o01 = *reinterpret_cast<const float4*>(&out[idx8 + 4]);
    float4 x0  = *reinterpret_cast<const float4*>(&xin[idx8]);
    float4 x1  = *reinterpret_cast<const float4*>(&xin[idx8 + 4]);
    float4 la0 = *reinterpret_cast<const float4*>(&lpart[b * NPIX + i]);
    float4 la1 = *reinterpret_cast<const float4*>(&lpart[b * NPIX + i + 4]);
    float4 lb0 = *reinterpret_cast<const float4*>(&lpart[(4 + b) * NPIX + i]);
    float4 lb1 = *reinterpret_cast<const float4*>(&lpart[(4 + b) * NPIX + i + 4]);
    const float g = gamma[0];
    float4 o;
    o.x = g * (o00.x + bf2f((unsigned short)o1v[0])) / (la0.x + lb0.x) + x0.x;
    o.y = g * (o00.y + bf2f((unsigned short)o1v[1])) / (la0.y + lb0.y) + x0.y;
    o.z = g * (o00.z + bf2f((unsigned short)o1v[2])) / (la0.z + lb0.z) + x0.z;
    o.w = g * (o00.w + bf2f((unsigned short)o1v[3])) / (la0.w + lb0.w) + x0.w;
    *reinterpret_cast<float4*>(&out[idx8]) = o;
    o.x = g * (o01.x + bf2f((unsigned short)o1v[4])) / (la1.x + lb1.x) + x1.x;
    o.y = g * (o01.y + bf2f((unsigned short)o1v[5])) / (la1.y + lb1.y) + x1.y;
    o.z = g * (o01.z + bf2f((unsigned short)o1v[6])) / (la1.z + lb1.z) + x1.z;
    o.w = g * (o01.w + bf2f((unsigned short)o1v[7])) / (la1.w + lb1.w) + x1.w;
    *reinterpret_cast<float4*>(&out[idx8 + 4]) = o;
}

extern "C" void kernel_launch(void* const* d_in, const int* in_sizes, int n_in,
                              void* d_out, int out_size, void* d_ws, size_t ws_size,
                              hipStream_t stream) {
    const float* x     = (const float*)d_in[0];
    const float* wq    = (const float*)d_in[1];
    const float* bq    = (const float*)d_in[2];
    const float* wk    = (const float*)d_in[3];
    const float* bk    = (const float*)d_in[4];
    const float* wv    = (const float*)d_in[5];
    const float* bv    = (const float*)d_in[6];
    const float* gamma = (const float*)d_in[7];
    float* out = (float*)d_out;

    unsigned short* qf    = (unsigned short*)d_ws;       // 1 MB
    unsigned short* kf    = qf + (size_t)524288;         // 1 MB
    unsigned short* vf    = kf + (size_t)524288;         // 8 MB
    unsigned short* wqh   = vf + (size_t)4194304;
    unsigned short* wql   = wqh + 8192;
    unsigned short* wkh   = wql + 8192;
    unsigned short* wkl   = wkh + 8192;
    unsigned short* wvh   = wkl + 8192;                  // 160 KB of weight frags
    unsigned short* opart = wvh + 65536;                 // 8.4 MB (jh1 bf16 partial O)
    float*          lpart = (float*)(opart + 4194304);   // 128 KB
    // total ~18.8 MB of d_ws

    wprep_kernel<<<dim3(16, 12), 64, 0, stream>>>(wq, wk, wv, wqh, wql, wkh, wkl, wvh);
    projall_kernel<<<dim3(128, 4), 512, 0, stream>>>(x, wqh, wql, wkh, wkl, wvh,
                                                     bq, bk, bv, qf, kf, vf);
    attnv_kernel<<<dim3(512), 512, 0, stream>>>(qf, kf, vf, opart, lpart, out);
    merge_kernel<<<dim3(2048), 256, 0, stream>>>(opart, lpart, x, gamma, out);
}

// Round 13
// 140.654 us; speedup vs baseline: 3.4105x; 3.4105x over previous
//
#include <hip/hip_runtime.h>
#include <hip/hip_bf16.h>

#define NPIX 4096
#define CIN  256
#define DK   32

typedef __attribute__((ext_vector_type(8))) short short8;     // 8 bf16 = one MFMA A/B frag reg group
typedef __attribute__((ext_vector_type(16))) float f32x16;    // 32x32 C/D frag

__device__ __forceinline__ unsigned short f2bf(float f) {
    unsigned int u = __float_as_uint(f);
    return (unsigned short)((u + 0x7fffu + ((u >> 16) & 1u)) >> 16);   // RNE
}
__device__ __forceinline__ float bf2f(unsigned short h) {
    return __uint_as_float(((unsigned int)h) << 16);
}
// packed fp32x2 -> bf16x2 via v_cvt_pk_bf16_f32 (RNE), low short = a
__device__ __forceinline__ unsigned int f2bf2(float a, float b) {
    __hip_bfloat162 h = __float22bfloat162_rn(make_float2(a, b));
    unsigned int u;
    __builtin_memcpy(&u, &h, 4);
    return u;
}

// ---------------------------------------------------------------------------
// Weight prep: wq/wk hi+residual B-frags, wv hi B-frags.
// grid (16 kchunks, 12), 64 threads.
__global__ void wprep_kernel(const float* __restrict__ wq, const float* __restrict__ wk,
                             const float* __restrict__ wv,
                             unsigned short* __restrict__ wqh, unsigned short* __restrict__ wql,
                             unsigned short* __restrict__ wkh, unsigned short* __restrict__ wkl,
                             unsigned short* __restrict__ wvh) {
    const int lane = threadIdx.x & 63, li = lane & 31, hi = lane >> 5;
    const int kc = blockIdx.x, y = blockIdx.y;
    if (y < 4) {
        const float* m = (y < 2) ? wq : wk;
        short8 h8, l8;
#pragma unroll
        for (int e = 0; e < 8; ++e) {
            float v = m[li * CIN + kc * 16 + hi * 8 + e];
            unsigned short hb = f2bf(v);
            h8[e] = (short)hb;
            l8[e] = (short)f2bf(v - bf2f(hb));
        }
        unsigned short* dst = (y == 0) ? wqh : (y == 1) ? wql : (y == 2) ? wkh : wkl;
        *reinterpret_cast<short8*>(&dst[kc * 512 + lane * 8]) = (y & 1) ? l8 : h8;
    } else {
        const int cblk = y - 4;
        short8 h8;
#pragma unroll
        for (int e = 0; e < 8; ++e)
            h8[e] = (short)f2bf(wv[(cblk * 32 + li) * CIN + kc * 16 + hi * 8 + e]);
        *reinterpret_cast<short8*>(&wvh[(cblk * 16 + kc) * 512 + lane * 8]) = h8;
    }
}

// ---------------------------------------------------------------------------
// Fused prep + Q/K/V projection. r10 structure, restaged in 2 phases of 128c
// (4 barriers instead of 8); same vectorized float4 staging, same frag math.
// grid (128, 4), block 512.
__global__ __launch_bounds__(512) void projall_kernel(
        const float* __restrict__ x,
        const unsigned short* __restrict__ wqh, const unsigned short* __restrict__ wql,
        const unsigned short* __restrict__ wkh, const unsigned short* __restrict__ wkl,
        const unsigned short* __restrict__ wvh,
        const float* __restrict__ bq, const float* __restrict__ bk, const float* __restrict__ bv,
        unsigned short* __restrict__ qfrag, unsigned short* __restrict__ kfrag,
        unsigned short* __restrict__ vfrag) {
    __shared__ float xs[128][36];                // 128c x 32n staging, 18 KB
    __shared__ unsigned short xhf[16 * 512];     // 16 KB
    __shared__ unsigned short xlf[16 * 512];     // 16 KB
    __shared__ unsigned short ts[2][32][40];     // 5 KB  (total ~55 KB)

    const int t = threadIdx.x, lane = t & 63, li = lane & 31, hi = lane >> 5, w = t >> 6;
    const int nblk = blockIdx.x, b = blockIdx.y;
    const int n0 = nblk * 32;

    for (int cb = 0; cb < 2; ++cb) {
        {   // stage 128c x 32n fp32: 1024 float4 units, 2/thread
#pragma unroll
            for (int k = 0; k < 2; ++k) {
                int id = t + k * 512;
                int c = id >> 3, n4 = (id & 7) * 4;
                float4 v = *reinterpret_cast<const float4*>(
                    &x[(size_t)(b * CIN + cb * 128 + c) * NPIX + n0 + n4]);
                xs[c][n4 + 0] = v.x; xs[c][n4 + 1] = v.y;
                xs[c][n4 + 2] = v.z; xs[c][n4 + 3] = v.w;
            }
        }
        __syncthreads();
        {   // wave w converts kc = cb*8 + w: both hi and residual frags
            short8 h8, l8;
#pragma unroll
            for (int e = 0; e < 8; ++e) {
                float v = xs[w * 16 + hi * 8 + e][li];
                unsigned short hb = f2bf(v);
                h8[e] = (short)hb;
                l8[e] = (short)f2bf(v - bf2f(hb));
            }
            const int kc = cb * 8 + w;
            *reinterpret_cast<short8*>(&xhf[kc * 512 + lane * 8]) = h8;
            *reinterpret_cast<short8*>(&xlf[kc * 512 + lane * 8]) = l8;
        }
        __syncthreads();
    }

    if (w < 2) {
        const unsigned short* wh = (w == 0) ? wqh : wkh;
        const unsigned short* wl = (w == 0) ? wql : wkl;
        const float* bias = (w == 0) ? bq : bk;
        f32x16 acc;
#pragma unroll
        for (int r = 0; r < 16; ++r) acc[r] = 0.f;
        for (int kc = 0; kc < 16; ++kc) {
            short8 ah = *reinterpret_cast<const short8*>(&xhf[kc * 512 + lane * 8]);
            short8 al = *reinterpret_cast<const short8*>(&xlf[kc * 512 + lane * 8]);
            short8 whf = *reinterpret_cast<const short8*>(&wh[kc * 512 + lane * 8]);
            short8 wlf = *reinterpret_cast<const short8*>(&wl[kc * 512 + lane * 8]);
            acc = __builtin_amdgcn_mfma_f32_32x32x16_bf16(ah, whf, acc, 0, 0, 0);
            acc = __builtin_amdgcn_mfma_f32_32x32x16_bf16(al, whf, acc, 0, 0, 0);
            acc = __builtin_amdgcn_mfma_f32_32x32x16_bf16(ah, wlf, acc, 0, 0, 0);
        }
        const float bs = bias[li];
#pragma unroll
        for (int r = 0; r < 16; ++r) {
            int row = (r & 3) + 8 * (r >> 2) + 4 * hi;
            ts[w][row][li] = f2bf(acc[r] + bs);
        }
        unsigned short* dstf = (w == 0) ? qfrag : kfrag;
#pragma unroll
        for (int dh = 0; dh < 2; ++dh) {
            short8 f = *reinterpret_cast<const short8*>(&ts[w][li][dh * 16 + hi * 8]);
            *reinterpret_cast<short8*>(
                &dstf[((size_t)(b * 128 + nblk) * 2 + dh) * 512 + lane * 8]) = f;
        }
    } else {
        const int w2 = w - 2;
        const int njob = (w2 < 2) ? 2 : 1;
        for (int jj = 0; jj < njob; ++jj) {
            const int cblk = w2 + jj * 6;
            f32x16 acc;
#pragma unroll
            for (int r = 0; r < 16; ++r) acc[r] = 0.f;
            for (int kc = 0; kc < 16; ++kc) {
                short8 xb = *reinterpret_cast<const short8*>(&xhf[kc * 512 + lane * 8]);
                short8 wf = *reinterpret_cast<const short8*>(&wvh[(cblk * 16 + kc) * 512 + lane * 8]);
                acc = __builtin_amdgcn_mfma_f32_32x32x16_bf16(xb, wf, acc, 0, 0, 0);
            }
            const float bvv = bv[cblk * 32 + li];
#pragma unroll
            for (int g = 0; g < 2; ++g) {
                short8 sv;
#pragma unroll
                for (int e = 0; e < 8; ++e) sv[e] = (short)f2bf(acc[g * 8 + e] + bvv);
                *reinterpret_cast<short8*>(
                    &vfrag[((size_t)(b * 8 + cblk) * 256 + nblk * 2 + g) * 512 + lane * 8]) = sv;
            }
        }
    }
}

// ---------------------------------------------------------------------------
// Fused attention — EXACT r10 version (measured 47.3 us, MfmaUtil 35%; r9/r11/
// r12 scheduling variants all regressed or were neutral — this is the local
// optimum of the structure). j-split, symmetric waves, K/V reg-prefetch 1 step.
__global__ __launch_bounds__(512, 4) void attnv_kernel(
        const unsigned short* __restrict__ qfrag, const unsigned short* __restrict__ kfrag,
        const unsigned short* __restrict__ vfrag, unsigned short* __restrict__ opart,
        float* __restrict__ lpart, float* __restrict__ out) {
    __shared__ unsigned short Ps[4 * 8 * 512];   // [it*2+buf][jg 8][lane*8], 32 KB
    __shared__ float sred[2][4][32];

    const int t = threadIdx.x, lane = t & 63, li = lane & 31, hi = lane >> 5, w = t >> 6;
    const int blk = blockIdx.x;
    const int xcd = blk & 7, slot = blk >> 3;
    const int jh = slot & 1, ps = slot >> 1;
    const int b = xcd >> 1;
    const int ipos = (xcd & 1) * 32 + ps;          // 64-i tile in [0,64)
    const int it = w >> 2, sl = w & 3;             // E unit
    const int cq = w;                              // PV unit (32 c)

    short8 qb0, qb1;
    {
        size_t qoff = ((size_t)(b * 128 + ipos * 2 + it) * 2) * 512 + lane * 8;
        qb0 = *reinterpret_cast<const short8*>(&qfrag[qoff]);
        qb1 = *reinterpret_cast<const short8*>(&qfrag[qoff + 512]);
    }
    float ssum = 0.f;

    f32x16 acc0, acc1;
#pragma unroll
    for (int r = 0; r < 16; ++r) { acc0[r] = 0.f; acc1[r] = 0.f; }

    short8 kp0, kp1;                               // K prefetch (for step s of do_E)
    short8 vp[8];                                  // V prefetch (for step s of PV)

    auto kload = [&](int s) {
        size_t koff = ((size_t)(b * 128 + jh * 64 + s * 4 + sl) * 2) * 512 + lane * 8;
        kp0 = *reinterpret_cast<const short8*>(&kfrag[koff]);
        kp1 = *reinterpret_cast<const short8*>(&kfrag[koff + 512]);
    };
    auto vload = [&](int s) {
        size_t vb = ((size_t)(b * 8 + cq) * 256 + jh * 128 + s * 8) * 512 + lane * 8;
#pragma unroll
        for (int kc = 0; kc < 8; ++kc)
            vp[kc] = *reinterpret_cast<const short8*>(&vfrag[vb + kc * 512]);
    };
    auto do_E = [&](int s) {                       // consumes kp0/kp1 (preloaded for s)
        f32x16 e;
#pragma unroll
        for (int r = 0; r < 16; ++r) e[r] = 0.f;
        e = __builtin_amdgcn_mfma_f32_32x32x16_bf16(kp0, qb0, e, 0, 0, 0);
        e = __builtin_amdgcn_mfma_f32_32x32x16_bf16(kp1, qb1, e, 0, 0, 0);
        const int buf = s & 1;
#pragma unroll
        for (int g = 0; g < 2; ++g) {
            float p0 = __expf(e[g * 8 + 0]), p1 = __expf(e[g * 8 + 1]);
            float p2 = __expf(e[g * 8 + 2]), p3 = __expf(e[g * 8 + 3]);
            float p4 = __expf(e[g * 8 + 4]), p5 = __expf(e[g * 8 + 5]);
            float p6 = __expf(e[g * 8 + 6]), p7 = __expf(e[g * 8 + 7]);
            ssum += ((p0 + p1) + (p2 + p3)) + ((p4 + p5) + (p6 + p7));
            uint4 pk;
            pk.x = f2bf2(p0, p1); pk.y = f2bf2(p2, p3);
            pk.z = f2bf2(p4, p5); pk.w = f2bf2(p6, p7);
            *reinterpret_cast<uint4*>(
                &Ps[((it * 2 + buf) * 8 + sl * 2 + g) * 512 + lane * 8]) = pk;
        }
    };

    kload(0);
    vload(0);
    do_E(0);
    kload(1);
    __syncthreads();                               // (1)

#pragma unroll 1
    for (int s = 0; s < 16; ++s) {
        if (s + 1 < 16) {
            do_E(s + 1);                           // writes buf (s+1)&1; kp holds step s+1
            if (s + 2 < 16) kload(s + 2);
        }
        const int buf = s & 1;
#pragma unroll
        for (int kc = 0; kc < 8; ++kc) {
            short8 B0 = *reinterpret_cast<const short8*>(&Ps[(buf * 8 + kc) * 512 + lane * 8]);
            short8 B1 = *reinterpret_cast<const short8*>(&Ps[((2 + buf) * 8 + kc) * 512 + lane * 8]);
            acc0 = __builtin_amdgcn_mfma_f32_32x32x16_bf16(vp[kc], B0, acc0, 0, 0, 0);
            acc1 = __builtin_amdgcn_mfma_f32_32x32x16_bf16(vp[kc], B1, acc1, 0, 0, 0);
        }
        if (s + 1 < 16) vload(s + 1);              // issued now, consumed after next barrier
        __syncthreads();                           // (2..17)
    }

    // row sums: wave w holds (it, sl) partial over its 32-j slice
    ssum += __shfl_xor(ssum, 32);
    if (lane < 32) sred[it][sl][li] = ssum;
    __syncthreads();                               // (18)
    if (sl == 0 && lane < 32) {
        float lt = sred[it][0][li] + sred[it][1][li] + sred[it][2][li] + sred[it][3][li];
        lpart[((size_t)jh * 4 + b) * NPIX + ipos * 64 + it * 32 + li] = lt;
    }

    // partial O (linear [b][c][i]): jh0 fp32 parked in out, jh1 bf16 in opart
#pragma unroll
    for (int itt = 0; itt < 2; ++itt) {
        const f32x16& A = itt ? acc1 : acc0;
#pragma unroll
        for (int r = 0; r < 16; ++r) {
            int c = cq * 32 + (r & 3) + 8 * (r >> 2) + 4 * hi;
            size_t idx = (size_t)(b * CIN + c) * NPIX + ipos * 64 + itt * 32 + li;
            if (jh == 0) out[idx] = A[r];
            else         opart[idx] = f2bf(A[r]);
        }
    }
}

// ---------------------------------------------------------------------------
// Merge: out = gamma * (O0 + O1) / (l0 + l1) + x.  ~56 MB streaming.
// grid 2048, block 256; thread handles 8 consecutive i (opart read = one 16B).
__global__ __launch_bounds__(256) void merge_kernel(
        const unsigned short* __restrict__ opart, const float* __restrict__ lpart,
        const float* __restrict__ xin, const float* __restrict__ gamma,
        float* __restrict__ out) {
    const size_t idx8 = ((size_t)blockIdx.x * 256 + threadIdx.x) * 8;
    const size_t i  = idx8 & (NPIX - 1);
    const size_t b  = idx8 >> 20;                 // idx8 / (CIN*NPIX)
    short8 o1v = *reinterpret_cast<const short8*>(&opart[idx8]);
    float4 o00 = *reinterpret_cast<const float4*>(&out[idx8]);
    float4 o01 = *reinterpret_cast<const float4*>(&out[idx8 + 4]);
    float4 x0  = *reinterpret_cast<const float4*>(&xin[idx8]);
    float4 x1  = *reinterpret_cast<const float4*>(&xin[idx8 + 4]);
    float4 la0 = *reinterpret_cast<const float4*>(&lpart[b * NPIX + i]);
    float4 la1 = *reinterpret_cast<const float4*>(&lpart[b * NPIX + i + 4]);
    float4 lb0 = *reinterpret_cast<const float4*>(&lpart[(4 + b) * NPIX + i]);
    float4 lb1 = *reinterpret_cast<const float4*>(&lpart[(4 + b) * NPIX + i + 4]);
    const float g = gamma[0];
    float4 o;
    o.x = g * (o00.x + bf2f((unsigned short)o1v[0])) / (la0.x + lb0.x) + x0.x;
    o.y = g * (o00.y + bf2f((unsigned short)o1v[1])) / (la0.y + lb0.y) + x0.y;
    o.z = g * (o00.z + bf2f((unsigned short)o1v[2])) / (la0.z + lb0.z) + x0.z;
    o.w = g * (o00.w + bf2f((unsigned short)o1v[3])) / (la0.w + lb0.w) + x0.w;
    *reinterpret_cast<float4*>(&out[idx8]) = o;
    o.x = g * (o01.x + bf2f((unsigned short)o1v[4])) / (la1.x + lb1.x) + x1.x;
    o.y = g * (o01.y + bf2f((unsigned short)o1v[5])) / (la1.y + lb1.y) + x1.y;
    o.z = g * (o01.z + bf2f((unsigned short)o1v[6])) / (la1.z + lb1.z) + x1.z;
    o.w = g * (o01.w + bf2f((unsigned short)o1v[7])) / (la1.w + lb1.w) + x1.w;
    *reinterpret_cast<float4*>(&out[idx8 + 4]) = o;
}

extern "C" void kernel_launch(void* const* d_in, const int* in_sizes, int n_in,
                              void* d_out, int out_size, void* d_ws, size_t ws_size,
                              hipStream_t stream) {
    const float* x     = (const float*)d_in[0];
    const float* wq    = (const float*)d_in[1];
    const float* bq    = (const float*)d_in[2];
    const float* wk    = (const float*)d_in[3];
    const float* bk    = (const float*)d_in[4];
    const float* wv    = (const float*)d_in[5];
    const float* bv    = (const float*)d_in[6];
    const float* gamma = (const float*)d_in[7];
    float* out = (float*)d_out;

    unsigned short* qf    = (unsigned short*)d_ws;       // 1 MB
    unsigned short* kf    = qf + (size_t)524288;         // 1 MB
    unsigned short* vf    = kf + (size_t)524288;         // 8 MB
    unsigned short* wqh   = vf + (size_t)4194304;
    unsigned short* wql   = wqh + 8192;
    unsigned short* wkh   = wql + 8192;
    unsigned short* wkl   = wkh + 8192;
    unsigned short* wvh   = wkl + 8192;                  // 160 KB of weight frags
    unsigned short* opart = wvh + 65536;                 // 8.4 MB (jh1 bf16 partial O)
    float*          lpart = (float*)(opart + 4194304);   // 128 KB
    // total ~18.8 MB of d_ws

    wprep_kernel<<<dim3(16, 12), 64, 0, stream>>>(wq, wk, wv, wqh, wql, wkh, wkl, wvh);
    projall_kernel<<<dim3(128, 4), 512, 0, stream>>>(x, wqh, wql, wkh, wkl, wvh,
                                                     bq, bk, bv, qf, kf, vf);
    attnv_kernel<<<dim3(512), 512, 0, stream>>>(qf, kf, vf, opart, lpart, out);
    merge_kernel<<<dim3(2048), 256, 0, stream>>>(opart, lpart, x, gamma, out);
}